// Round 7
// baseline (29.637 us; speedup 1.0000x reference)
//
#include <hip/hip_runtime.h>

#define IN_F 4096
#define OUT_F 11008
#define GROUPSIZE 128
#define NGROUPS 32
#define QROWS 512
#define ZCOLS 1376

#define COLS_PB 16            // columns per block
#define NBLOCKS (OUT_F / COLS_PB)   // 688

// Single-dispatch fused GPTQ GEMV.
// Block: 512 threads = 16 cols x 32 k-parts; thread (c, g) handles group g
// (16 packed int32s = 128 K) of column col0+c. LDS tree-reduce + bias + store.
__global__ __launch_bounds__(512, 6) void gptq_fused(
    const float* __restrict__ x,       // [4, IN_F]
    const float* __restrict__ scales,  // [NGROUPS, OUT_F]
    const float* __restrict__ bias,    // [OUT_F]
    const int*   __restrict__ qweight, // [QROWS, OUT_F]
    const int*   __restrict__ qzeros,  // [NGROUPS, ZCOLS]
    float*       __restrict__ out)     // [4, OUT_F]
{
    __shared__ float part[NGROUPS][4][COLS_PB];   // 8 KB

    const int tid = threadIdx.x;
    const int c   = tid & (COLS_PB - 1);          // 0..15
    const int g   = tid >> 4;                     // 0..31 = GPTQ group
    const int col = blockIdx.x * COLS_PB + c;

    // zero + scale for (g, col)
    const unsigned qz = (unsigned)qzeros[g * ZCOLS + (col >> 3)];
    const float z  = (float)(((qz >> (4u * (unsigned)(col & 7))) & 0xFu) + 1u);
    const float sc = scales[g * OUT_F + col];

    const int row0 = g * 16;                      // first packed row of group

    // 8 independent accumulator chains: [m][t&1]
    float ga[4][2] = {{0.f,0.f},{0.f,0.f},{0.f,0.f},{0.f,0.f}};

    #pragma unroll
    for (int t = 0; t < 16; ++t) {
        const int row = row0 + t;
        const unsigned w = (unsigned)qweight[row * OUT_F + col];

        const unsigned lo = w & 0x0F0F0F0Fu;          // nibbles 0,2,4,6
        const unsigned hi = (w >> 4) & 0x0F0F0F0Fu;   // nibbles 1,3,5,7
        float d[8];
        d[0] = (float)(lo & 0xFFu) - z;          d[1] = (float)(hi & 0xFFu) - z;
        d[2] = (float)((lo >> 8) & 0xFFu) - z;   d[3] = (float)((hi >> 8) & 0xFFu) - z;
        d[4] = (float)((lo >> 16) & 0xFFu) - z;  d[5] = (float)((hi >> 16) & 0xFFu) - z;
        d[6] = (float)(lo >> 24) - z;            d[7] = (float)(hi >> 24) - z;

        const int k0 = row * 8;
        const int p  = t & 1;
        #pragma unroll
        for (int m = 0; m < 4; ++m) {
            const float4 a = *(const float4*)(x + m * IN_F + k0);
            const float4 b = *(const float4*)(x + m * IN_F + k0 + 4);
            ga[m][p] += a.x * d[0];
            ga[m][p] += a.y * d[1];
            ga[m][p] += a.z * d[2];
            ga[m][p] += a.w * d[3];
            ga[m][p] += b.x * d[4];
            ga[m][p] += b.y * d[5];
            ga[m][p] += b.z * d[6];
            ga[m][p] += b.w * d[7];
        }
    }

    #pragma unroll
    for (int m = 0; m < 4; ++m)
        part[g][m][c] = sc * (ga[m][0] + ga[m][1]);

    __syncthreads();

    // 64 threads: (m = tid>>4, c = tid&15) sum the 32 group partials.
    if (tid < 64) {
        const int m  = tid >> 4;
        const int cc = tid & 15;
        float s0 = 0.f, s1 = 0.f, s2 = 0.f, s3 = 0.f;
        #pragma unroll
        for (int k = 0; k < NGROUPS; k += 4) {
            s0 += part[k + 0][m][cc];
            s1 += part[k + 1][m][cc];
            s2 += part[k + 2][m][cc];
            s3 += part[k + 3][m][cc];
        }
        const int n = blockIdx.x * COLS_PB + cc;
        out[m * OUT_F + n] = (s0 + s1) + (s2 + s3) + bias[n];
    }
}

extern "C" void kernel_launch(void* const* d_in, const int* in_sizes, int n_in,
                              void* d_out, int out_size, void* d_ws, size_t ws_size,
                              hipStream_t stream) {
    const float* x       = (const float*)d_in[0];
    const float* scales  = (const float*)d_in[1];
    const float* bias    = (const float*)d_in[2];
    const int*   qweight = (const int*)d_in[3];
    const int*   qzeros  = (const int*)d_in[4];
    float*       out     = (float*)d_out;

    gptq_fused<<<NBLOCKS, 512, 0, stream>>>(x, scales, bias, qweight, qzeros, out);
}

// Round 8
// 19.632 us; speedup vs baseline: 1.5096x; 1.5096x over previous
//
#include <hip/hip_runtime.h>

#define IN_F 4096
#define OUT_F 11008
#define GROUPSIZE 128
#define NGROUPS 32
#define QROWS 512
#define ZCOLS 1376

#define WS_NEW_BYTES ((size_t)NGROUPS * 4 * OUT_F * sizeof(float))   // 5.6 MB
#define WS_OLD_BYTES ((size_t)8 * 4 * OUT_F * sizeof(float))         // 1.4 MB

// ============ Stage 1: register-resident dequant GEMV ============
// Grid (172, 32) = 5504 blocks, 256 threads = 16 rows x 16 col-quads.
// Block (bx, g): group g (16 packed rows), cols [bx*64, +64).
// Thread (rl = tid>>4, cq = tid&15): packed row g*16+rl, cols bx*64+cq*4..+3.
//   - x[4][8] preloaded to VGPRs (the thread's entire x slice)
//   - one dwordx4 qweight load (4 cols), z/s in regs
//   - compute loop touches no memory at all
__global__ __launch_bounds__(256) void gptq_s1_reg(
    const float* __restrict__ x,       // [4, IN_F]
    const float* __restrict__ scales,  // [NGROUPS, OUT_F]
    const int*   __restrict__ qweight, // [QROWS, OUT_F]
    const int*   __restrict__ qzeros,  // [NGROUPS, ZCOLS]
    float*       __restrict__ ws)      // [NGROUPS, 4, OUT_F]
{
    __shared__ float part[16][4][64];  // [row_local][token][col] = 16 KB

    const int tid = threadIdx.x;
    const int rl  = tid >> 4;          // 0..15 row within group
    const int cq  = tid & 15;          // col quad
    const int bx  = blockIdx.x;
    const int g   = blockIdx.y;
    const int c0  = bx * 64 + cq * 4;
    const int row = g * 16 + rl;       // packed qweight row
    const int k0  = row * 8;

    // ---- issue ALL loads upfront (independent -> deep MLP) ----
    const int4 w4 = *(const int4*)(qweight + (size_t)row * OUT_F + c0);
    const unsigned qz = (unsigned)qzeros[g * ZCOLS + (c0 >> 3)];
    const float4 s4 = *(const float4*)(scales + g * OUT_F + c0);
    float4 xa[4], xb[4];
    #pragma unroll
    for (int m = 0; m < 4; ++m) {
        xa[m] = *(const float4*)(x + m * IN_F + k0);
        xb[m] = *(const float4*)(x + m * IN_F + k0 + 4);
    }

    const unsigned bsh = 4u * (unsigned)(c0 & 7);   // 0 or 16
    const unsigned wv[4] = {(unsigned)w4.x, (unsigned)w4.y,
                            (unsigned)w4.z, (unsigned)w4.w};

    float acc[4][4];                   // [m][c]
    #pragma unroll
    for (int m = 0; m < 4; ++m)
        #pragma unroll
        for (int c = 0; c < 4; ++c) acc[m][c] = 0.f;

    // ---- pure-register compute: 4 cols x (unpack + 32 FMA) ----
    #pragma unroll
    for (int c = 0; c < 4; ++c) {
        const float z = (float)(((qz >> (bsh + 4u * c)) & 0xFu) + 1u);
        const unsigned w  = wv[c];
        const unsigned lo = w & 0x0F0F0F0Fu;          // nibbles 0,2,4,6
        const unsigned hi = (w >> 4) & 0x0F0F0F0Fu;   // nibbles 1,3,5,7
        float d[8];
        d[0] = (float)(lo & 0xFFu) - z;          d[1] = (float)(hi & 0xFFu) - z;
        d[2] = (float)((lo >> 8) & 0xFFu) - z;   d[3] = (float)((hi >> 8) & 0xFFu) - z;
        d[4] = (float)((lo >> 16) & 0xFFu) - z;  d[5] = (float)((hi >> 16) & 0xFFu) - z;
        d[6] = (float)(lo >> 24) - z;            d[7] = (float)(hi >> 24) - z;
        #pragma unroll
        for (int m = 0; m < 4; ++m) {
            acc[m][c] += xa[m].x * d[0];
            acc[m][c] += xa[m].y * d[1];
            acc[m][c] += xa[m].z * d[2];
            acc[m][c] += xa[m].w * d[3];
            acc[m][c] += xb[m].x * d[4];
            acc[m][c] += xb[m].y * d[5];
            acc[m][c] += xb[m].z * d[6];
            acc[m][c] += xb[m].w * d[7];
        }
    }

    // ---- scale + LDS epilogue ----
    #pragma unroll
    for (int m = 0; m < 4; ++m) {
        float4 r;
        r.x = acc[m][0] * s4.x;
        r.y = acc[m][1] * s4.y;
        r.z = acc[m][2] * s4.z;
        r.w = acc[m][3] * s4.w;
        *(float4*)&part[rl][m][cq * 4] = r;
    }
    __syncthreads();

    // reduce 16 rows: thread -> (m = tid>>6, col = tid&63)
    const int m   = tid >> 6;
    const int col = tid & 63;
    float t0 = 0.f, t1 = 0.f, t2 = 0.f, t3 = 0.f;
    #pragma unroll
    for (int r = 0; r < 16; r += 4) {
        t0 += part[r + 0][m][col];
        t1 += part[r + 1][m][col];
        t2 += part[r + 2][m][col];
        t3 += part[r + 3][m][col];
    }
    ws[(size_t)(g * 4 + m) * OUT_F + bx * 64 + col] = (t0 + t1) + (t2 + t3);
}

// ============ Stage 2: reduce NGROUPS partials + bias (proven) ============
__global__ __launch_bounds__(256) void gptq_s2(
    const float* __restrict__ ws,      // [NGROUPS, 4, OUT_F]
    const float* __restrict__ bias,
    float*       __restrict__ out)     // [4, OUT_F]
{
    const int n = blockIdx.x * 256 + threadIdx.x;   // 11008 = 43*256
    const int m = blockIdx.y;
    float s0 = bias[n], s1 = 0.f, s2 = 0.f, s3 = 0.f;
    #pragma unroll
    for (int g = 0; g < NGROUPS; g += 4) {
        s0 += ws[(size_t)((g + 0) * 4 + m) * OUT_F + n];
        s1 += ws[(size_t)((g + 1) * 4 + m) * OUT_F + n];
        s2 += ws[(size_t)((g + 2) * 4 + m) * OUT_F + n];
        s3 += ws[(size_t)((g + 3) * 4 + m) * OUT_F + n];
    }
    out[m * OUT_F + n] = (s0 + s1) + (s2 + s3);
}

// ============ Fallback A: round-2 proven two-stage (ws >= 1.4 MB) ============
__global__ __launch_bounds__(256) void gptq_partial_kernel(
    const float* __restrict__ x, const float* __restrict__ scales,
    const int* __restrict__ qweight, const int* __restrict__ qzeros,
    float* __restrict__ ws)
{
    __shared__ float part[4][4][64];
    const int tid = threadIdx.x;
    const int col = tid & 63;
    const int kp  = tid >> 6;
    const int n   = blockIdx.x * 64 + col;
    const int g   = blockIdx.y * 4 + kp;
    const int gu  = __builtin_amdgcn_readfirstlane(g);
    const unsigned qz = (unsigned)qzeros[g * ZCOLS + (n >> 3)];
    const float zf = (float)(((qz >> (4u * (unsigned)(n & 7))) & 0xFu) + 1u);
    const float sc = scales[g * OUT_F + n];
    float ga[4] = {0.f, 0.f, 0.f, 0.f};
    const int kkbase = gu * (GROUPSIZE / 8);
    #pragma unroll
    for (int t = 0; t < GROUPSIZE / 8; ++t) {
        const int kk = kkbase + t;
        const unsigned w = (unsigned)qweight[kk * OUT_F + n];
        const unsigned lo = w & 0x0F0F0F0Fu;
        const unsigned hi = (w >> 4) & 0x0F0F0F0Fu;
        float q[8];
        q[0] = (float)(lo & 0xFFu);         q[1] = (float)(hi & 0xFFu);
        q[2] = (float)((lo >> 8) & 0xFFu);  q[3] = (float)((hi >> 8) & 0xFFu);
        q[4] = (float)((lo >> 16) & 0xFFu); q[5] = (float)((hi >> 16) & 0xFFu);
        q[6] = (float)(lo >> 24);           q[7] = (float)(hi >> 24);
        const int k0 = kk * 8;
        #pragma unroll
        for (int j = 0; j < 8; ++j) {
            const float d = q[j] - zf;
            #pragma unroll
            for (int m = 0; m < 4; ++m) ga[m] += x[m * IN_F + k0 + j] * d;
        }
    }
    #pragma unroll
    for (int m = 0; m < 4; ++m) part[kp][m][col] = sc * ga[m];
    __syncthreads();
    const int m = tid >> 6;
    const int c = tid & 63;
    const int nn = blockIdx.x * 64 + c;
    const float s = part[0][m][c] + part[1][m][c] + part[2][m][c] + part[3][m][c];
    ws[(blockIdx.y * 4 + m) * OUT_F + nn] = s;
}

__global__ __launch_bounds__(256) void gptq_reduce8(
    const float* __restrict__ ws, const float* __restrict__ bias,
    float* __restrict__ out)
{
    const int n = blockIdx.x * 256 + threadIdx.x;
    const int m = blockIdx.y;
    float s = bias[n];
    #pragma unroll
    for (int ks = 0; ks < 8; ++ks) s += ws[(ks * 4 + m) * OUT_F + n];
    out[m * OUT_F + n] = s;
}

extern "C" void kernel_launch(void* const* d_in, const int* in_sizes, int n_in,
                              void* d_out, int out_size, void* d_ws, size_t ws_size,
                              hipStream_t stream) {
    const float* x       = (const float*)d_in[0];
    const float* scales  = (const float*)d_in[1];
    const float* bias    = (const float*)d_in[2];
    const int*   qweight = (const int*)d_in[3];
    const int*   qzeros  = (const int*)d_in[4];
    float*       out     = (float*)d_out;

    if (ws_size >= WS_NEW_BYTES) {
        float* ws = (float*)d_ws;
        dim3 g1(OUT_F / 64, NGROUPS);   // (172, 32) = 5504 blocks
        gptq_s1_reg<<<g1, 256, 0, stream>>>(x, scales, qweight, qzeros, ws);
        dim3 g2(OUT_F / 256, 4);
        gptq_s2<<<g2, 256, 0, stream>>>(ws, bias, out);
    } else if (ws_size >= WS_OLD_BYTES) {
        float* ws = (float*)d_ws;
        dim3 g1(OUT_F / 64, 8);
        gptq_partial_kernel<<<g1, 256, 0, stream>>>(x, scales, qweight, qzeros, ws);
        dim3 g2(OUT_F / 256, 4);
        gptq_reduce8<<<g2, 256, 0, stream>>>(ws, bias, out);
    }
}